// Round 5
// baseline (194.179 us; speedup 1.0000x reference)
//
#include <hip/hip_runtime.h>
#include <hip/hip_bf16.h>
#include <stdint.h>

#define B_ 32
#define T_ 1024
#define C_ 768
#define H_ 64

typedef float f32x4 __attribute__((ext_vector_type(4)));
typedef short bf16x8 __attribute__((ext_vector_type(8)));

static __device__ __forceinline__ unsigned short f2bf(float f) {
    uint32_t u = __float_as_uint(f);
    u += 0x7fffu + ((u >> 16) & 1u);   // RNE
    return (unsigned short)(u >> 16);
}

// ---------------- Kernel A0: pack Wq|Wk|Wv (fp32) -> W_all[192][768] bf16 ----------------
__global__ void wpack(const float* __restrict__ Wq, const float* __restrict__ Wk,
                      const float* __restrict__ Wv, unsigned short* __restrict__ Wall) {
    int i = blockIdx.x * 256 + threadIdx.x;      // one float4 per thread
    int base = i * 4;
    if (base >= 192 * 768) return;
    int r = base / 768, c = base % 768;
    const float* src = (r < 64) ? (Wq + r * 768 + c)
                     : (r < 128) ? (Wk + (r - 64) * 768 + c)
                                 : (Wv + (r - 128) * 768 + c);
    float4 v = *(const float4*)src;
    ushort4 o;
    o.x = f2bf(v.x); o.y = f2bf(v.y); o.z = f2bf(v.z); o.w = f2bf(v.w);
    *(ushort4*)(Wall + base) = o;
}

// ---------------- Kernel A1: QKV projection via bf16 MFMA ----------------
// Block: 256 thr (4 waves), 64 rows x 192 cols, BK=32.
// q,k written [B][T][64] bf16 (LDS-transpose epilogue); v written transposed [B][64][T] bf16.
#define XS 40
#define WS 40

__global__ __launch_bounds__(256)
void qkv_proj(const float* __restrict__ x, const unsigned short* __restrict__ Wall,
              unsigned short* __restrict__ qb, unsigned short* __restrict__ kb,
              unsigned short* __restrict__ vt) {
    __shared__ unsigned short x_t[64 * XS];
    __shared__ unsigned short w_t[192 * WS];
    __shared__ unsigned short tr[4][16 * 20];    // per-wave transpose patch

    const int tid = threadIdx.x;
    const int lane = tid & 63, w = tid >> 6;
    const int rowbase = blockIdx.x * 64;         // row in flattened [B*T]
    const int mh = (w >> 1) * 2;                 // 2 m-tiles of 16 rows per wave
    const int nh = (w & 1) * 6;                  // 6 n-tiles of 16 cols per wave
    const int fr = lane & 15, fg = lane >> 4;

    f32x4 acc[2][6] = {};

    for (int ks = 0; ks < 768; ks += 32) {
        {   // stage X: 64 rows x 32 k, fp32 -> bf16
            int r = tid >> 3, cp = tid & 7;
            const float* xp = x + (size_t)(rowbase + r) * 768 + ks + cp * 4;
            unsigned short* dst = x_t + r * XS + cp * 4;
#pragma unroll
            for (int rr = 0; rr < 2; rr++) {
                float4 v = *(const float4*)(xp + (size_t)rr * 32 * 768);
                ushort4 o; o.x = f2bf(v.x); o.y = f2bf(v.y); o.z = f2bf(v.z); o.w = f2bf(v.w);
                *(ushort4*)(dst + rr * 32 * XS) = o;
            }
        }
        {   // stage W: 192 rows x 32 k, bf16 copy
            int n0 = tid >> 2, cp = tid & 3;
            const unsigned short* wp = Wall + (size_t)n0 * 768 + ks + cp * 8;
            unsigned short* dst = w_t + n0 * WS + cp * 8;
#pragma unroll
            for (int p = 0; p < 3; p++) {
                int4 v = *(const int4*)(wp + (size_t)p * 64 * 768);
                *(int4*)(dst + p * 64 * WS) = v;
            }
        }
        __syncthreads();

        bf16x8 afr[2], bfr[6];
#pragma unroll
        for (int i = 0; i < 2; i++)
            afr[i] = *(const bf16x8*)(x_t + ((mh + i) * 16 + fr) * XS + fg * 8);
#pragma unroll
        for (int j = 0; j < 6; j++)
            bfr[j] = *(const bf16x8*)(w_t + ((nh + j) * 16 + fr) * WS + fg * 8);
#pragma unroll
        for (int i = 0; i < 2; i++)
#pragma unroll
            for (int j = 0; j < 6; j++)
                acc[i][j] = __builtin_amdgcn_mfma_f32_16x16x32_bf16(afr[i], bfr[j], acc[i][j], 0, 0, 0);
        __syncthreads();
    }

    // epilogue: C-frag (m89 layout) col=lane&15, row=(lane>>4)*4+reg
    const int b  = rowbase >> 10;
    const int t0 = rowbase & 1023;
    unsigned short* trp = &tr[w][0];
#pragma unroll
    for (int i = 0; i < 2; i++) {
        const int tb = t0 + (mh + i) * 16;
#pragma unroll
        for (int j = 0; j < 6; j++) {
            const int nc = (nh + j) * 16;        // global col 0..191
            if (nc < 128) {
                // q or k: [T][64] layout -> transpose via wave-private LDS
                unsigned short* dstb = (nc < 64) ? qb : kb;
                const int col = nc & 63;
#pragma unroll
                for (int r = 0; r < 4; r++)
                    trp[(fg * 4 + r) * 20 + fr] = f2bf(acc[i][j][r]);
                int row = lane >> 2, seg = lane & 3;
                ushort4 rv = *(const ushort4*)(trp + row * 20 + seg * 4);
                *(ushort4*)(dstb + (size_t)(b * 1024 + tb + row) * 64 + col + seg * 4) = rv;
            } else {
                // v: [64][T] transposed layout is the natural C-frag store
                const int h = nc - 128 + fr;
                ushort4 o;
                o.x = f2bf(acc[i][j][0]); o.y = f2bf(acc[i][j][1]);
                o.z = f2bf(acc[i][j][2]); o.w = f2bf(acc[i][j][3]);
                *(ushort4*)(vt + (size_t)(b * 64 + h) * 1024 + tb + fg * 4) = o;
            }
        }
    }
}

// ---------------- Kernel B: causal flash attention via MFMA ----------------
// Block = 256 thr (4 waves) = 64 contiguous q-rows; all waves share chunk count bx+1.
// Per chunk: stage K[64k][64h] + V^T[64h][64k] to LDS (XOR-16B-slot swizzle on write).
// S^T = K·Q^T (8 MFMAs) -> softmax in C-frag regs (2 shfl per reduce) -> P^T via
// wave-private LDS patch -> O^T += V^T·P^T (8 MFMAs). Epilogue: scale by 1/l, float4 stores.
__global__ __launch_bounds__(256)
void attn_mfma(const unsigned short* __restrict__ qbuf, const unsigned short* __restrict__ kbuf,
               const unsigned short* __restrict__ vtb, float* __restrict__ out) {
    __shared__ unsigned short ldsK[64 * 64];     // [key][h], 16B slots swizzled by key&7
    __shared__ unsigned short ldsV[64 * 64];     // [h][key], 16B slots swizzled by h&7
    __shared__ unsigned short ldsP[4][16 * 72];  // per-wave P^T patch [q][k], stride 72 (144B rows)

    const int tid  = threadIdx.x;
    const int lane = tid & 63, w = tid >> 6;
    const int q16 = lane & 15, g = lane >> 4;

    // load-balance pairing: concurrent blocks get complementary diagonal cost (bx, 15-bx)
    const int fid = blockIdx.x;
    const int p = fid & 255, half = fid >> 8;
    const int bx = half ? (15 - (p & 15)) : (p & 15);
    const int b  = (p >> 4) + (half << 4);

    const int qrow0 = bx * 64 + w * 16;          // wave's q-tile base within batch

    // hoist Q B-frags: lane holds col q16, h = 32s + 8g .. +8
    const unsigned short* qp = qbuf + ((size_t)(b * 1024 + qrow0 + q16) << 6);
    bf16x8 qfrag[2];
    qfrag[0] = *(const bf16x8*)(qp + (g << 3));
    qfrag[1] = *(const bf16x8*)(qp + 32 + (g << 3));

    f32x4 accO[4] = {};                          // O^T h-tiles (16 h each)
    float m_run = -INFINITY, l_run = 0.f;

    for (int ci = 0; ci <= bx; ci++) {
        const int kbase = ci << 6;
        // ---- cooperative stage (reg-staged; swizzled LDS writes; coalesced global reads) ----
#pragma unroll
        for (int rI = 0; rI < 2; rI++) {
            int t2 = tid + (rI << 8);            // 0..511: row = t2>>3, 16B slot = t2&7
            int row = t2 >> 3, sl = t2 & 7;
            int4 kv = *(const int4*)(kbuf + ((size_t)(b * 1024 + kbase + row) << 6) + (sl << 3));
            *(int4*)(ldsK + (row << 6) + ((sl ^ (row & 7)) << 3)) = kv;
            int4 vv = *(const int4*)(vtb + ((size_t)(b * 64 + row) << 10) + kbase + (sl << 3));
            *(int4*)(ldsV + (row << 6) + ((sl ^ (row & 7)) << 3)) = vv;
        }
        __syncthreads();

        // ---- QK^T: S^T[k][q], 4 key-tiles x 2 h-steps ----
        f32x4 accS[4] = {};
#pragma unroll
        for (int t = 0; t < 4; t++) {
            const unsigned short* kr = ldsK + (((t << 4) + q16) << 6);
#pragma unroll
            for (int s = 0; s < 2; s++) {
                bf16x8 af = *(const bf16x8*)(kr + ((((s << 2) + g) ^ (q16 & 7)) << 3));
                accS[t] = __builtin_amdgcn_mfma_f32_16x16x32_bf16(af, qfrag[s], accS[t], 0, 0, 0);
            }
        }

        // ---- scale + causal mask + chunk max (in C-frag regs) ----
        const bool diag = (ci == bx);
        const int qlim = (w << 4) + q16;         // local query index within block
        float mloc = -INFINITY;
#pragma unroll
        for (int t = 0; t < 4; t++)
#pragma unroll
            for (int r = 0; r < 4; r++) {
                float s = accS[t][r] * 0.125f;   // 1/sqrt(64)
                int kl = (t << 4) + (g << 2) + r;
                if (diag && kl > qlim) s = -INFINITY;
                accS[t][r] = s;
                mloc = fmaxf(mloc, s);
            }
        mloc = fmaxf(mloc, __shfl_xor(mloc, 16, 64));
        mloc = fmaxf(mloc, __shfl_xor(mloc, 32, 64));
        const float m_new = fmaxf(m_run, mloc);
        const float alpha = __expf(m_run - m_new);   // first chunk: exp(-inf)=0
        m_run = m_new;

        // ---- P = exp(S-m), pack bf16, write P^T patch [q][k] ----
        unsigned short* pl = &ldsP[w][0];
        float lloc = 0.f;
#pragma unroll
        for (int t = 0; t < 4; t++) {
            float p0 = __expf(accS[t][0] - m_new);
            float p1 = __expf(accS[t][1] - m_new);
            float p2 = __expf(accS[t][2] - m_new);
            float p3 = __expf(accS[t][3] - m_new);
            lloc += (p0 + p1) + (p2 + p3);
            uint2 pk;
            pk.x = (uint32_t)f2bf(p0) | ((uint32_t)f2bf(p1) << 16);
            pk.y = (uint32_t)f2bf(p2) | ((uint32_t)f2bf(p3) << 16);
            *(uint2*)(pl + q16 * 72 + (t << 4) + (g << 2)) = pk;   // keys 16t+4g..+3 of col q16
        }
        lloc += __shfl_xor(lloc, 16, 64);
        lloc += __shfl_xor(lloc, 32, 64);
        l_run = l_run * alpha + lloc;

        // ---- rescale O^T, then O^T += V^T · P^T ----
#pragma unroll
        for (int t = 0; t < 4; t++) accO[t] *= alpha;

        bf16x8 pf0 = *(const bf16x8*)(pl + q16 * 72 + (g << 3));        // k = 8g..+8
        bf16x8 pf1 = *(const bf16x8*)(pl + q16 * 72 + 32 + (g << 3));   // k = 32+8g..+8
#pragma unroll
        for (int tp = 0; tp < 4; tp++) {
            const unsigned short* vr = ldsV + (((tp << 4) + q16) << 6);
            bf16x8 af0 = *(const bf16x8*)(vr + ((g ^ (q16 & 7)) << 3));
            accO[tp] = __builtin_amdgcn_mfma_f32_16x16x32_bf16(af0, pf0, accO[tp], 0, 0, 0);
            bf16x8 af1 = *(const bf16x8*)(vr + (((4 + g) ^ (q16 & 7)) << 3));
            accO[tp] = __builtin_amdgcn_mfma_f32_16x16x32_bf16(af1, pf1, accO[tp], 0, 0, 0);
        }
        __syncthreads();
    }

    // ---- epilogue: out[b][t][h] = O^T[h][q]/l ----
    const float inv = 1.0f / l_run;
    float* op = out + ((size_t)(b * 1024 + qrow0 + q16) << 6);
#pragma unroll
    for (int tp = 0; tp < 4; tp++) {
        float4 o4;
        o4.x = accO[tp][0] * inv; o4.y = accO[tp][1] * inv;
        o4.z = accO[tp][2] * inv; o4.w = accO[tp][3] * inv;
        *(float4*)(op + (tp << 4) + (g << 2)) = o4;    // h = 16tp + 4g .. +3
    }
}

// ---------------- launch ----------------
extern "C" void kernel_launch(void* const* d_in, const int* in_sizes, int n_in,
                              void* d_out, int out_size, void* d_ws, size_t ws_size,
                              hipStream_t stream) {
    const float* x  = (const float*)d_in[0];
    const float* Wq = (const float*)d_in[1];
    const float* Wk = (const float*)d_in[2];
    const float* Wv = (const float*)d_in[3];

    unsigned short* Wall = (unsigned short*)d_ws;              // 192*768 bf16
    unsigned short* qbuf = Wall + 192 * 768;                   // [B][T][64] bf16
    unsigned short* kbuf = qbuf + (size_t)B_ * T_ * H_;        // [B][T][64] bf16
    unsigned short* vtb  = kbuf + (size_t)B_ * T_ * H_;        // [B][64][T] bf16
    float* out = (float*)d_out;

    wpack<<<144, 256, 0, stream>>>(Wq, Wk, Wv, Wall);
    qkv_proj<<<512, 256, 0, stream>>>(x, Wall, qbuf, kbuf, vtb);
    attn_mfma<<<512, 256, 0, stream>>>(qbuf, kbuf, vtb, out);
}